// Round 1
// baseline (121.794 us; speedup 1.0000x reference)
//
#include <hip/hip_runtime.h>
#include <cstdint>

#define NQ    8192
#define NNEG  16384
#define DIM   128
#define SPLIT 8
#define CHUNK (NNEG / SPLIT)          // 2048
// (1/TAU) * log2(e): MFMA output is directly the base-2 exponent
#define K_SCALE 7.2134752044448169f
#define LN2     0.69314718055994531f

typedef __attribute__((ext_vector_type(8))) __bf16 bf16x8;
typedef __attribute__((ext_vector_type(4))) float  f32x4;

__device__ inline void async_load16(const void* g, void* l) {
    __builtin_amdgcn_global_load_lds(
        (const __attribute__((address_space(1))) void*)g,
        (__attribute__((address_space(3))) void*)l, 16, 0, 0);
}

__device__ inline unsigned short f2bf(float x) {
    uint32_t u = __float_as_uint(x);
    u += 0x7fffu + ((u >> 16) & 1u);      // round-to-nearest-even
    return (unsigned short)(u >> 16);
}

__device__ inline float waveReduceSum(float v) {
#pragma unroll
    for (int m = 32; m >= 1; m >>= 1) v += __shfl_xor(v, m, 64);
    return v;
}

// ---------------- kernel 1: convert + zero output ----------------
__global__ __launch_bounds__(256) void iw_prep(
    const float* __restrict__ q, const float* __restrict__ neg,
    unsigned short* __restrict__ qb, unsigned short* __restrict__ nb,
    float* __restrict__ out)
{
    const int i = blockIdx.x * 256 + threadIdx.x;
    if (i == 0) out[0] = 0.f;
    constexpr int QG = NQ * DIM / 4;      // 262144 float4 groups of Q
    if (i < QG) {
        float4 v = ((const float4*)q)[i];
        ushort4 o;
        o.x = f2bf(v.x * K_SCALE); o.y = f2bf(v.y * K_SCALE);
        o.z = f2bf(v.z * K_SCALE); o.w = f2bf(v.w * K_SCALE);
        ((ushort4*)qb)[i] = o;
    } else {
        int j = i - QG;                   // < 524288
        float4 v = ((const float4*)neg)[j];
        ushort4 o;
        o.x = f2bf(v.x); o.y = f2bf(v.y); o.z = f2bf(v.z); o.w = f2bf(v.w);
        ((ushort4*)nb)[j] = o;
    }
}

// ---------------- kernel 2: positive logits (f32) ----------------
__global__ __launch_bounds__(256) void iw_pos(
    const float* __restrict__ q, const float* __restrict__ p,
    float* __restrict__ out)
{
    const int tid = threadIdx.x;
    float acc = 0.f;
    const float4* q4 = (const float4*)q;
    const float4* p4 = (const float4*)p;
    const int n4 = NQ * DIM / 4;
    for (int i = blockIdx.x * 256 + tid; i < n4; i += 128 * 256) {
        float4 a = q4[i], b = p4[i];
        acc = fmaf(a.x, b.x, fmaf(a.y, b.y, fmaf(a.z, b.z, fmaf(a.w, b.w, acc))));
    }
    acc = waveReduceSum(acc);
    __shared__ float red[4];
    if ((tid & 63) == 0) red[tid >> 6] = acc;
    __syncthreads();
    if (tid == 0) {
        float s = red[0] + red[1] + red[2] + red[3];
        atomicAdd(out, s * (-1.0f / (0.2f * (float)NQ)));
    }
}

// ---------------- kernel 3: flash-LSE main ----------------
// grid (64, 8): blockIdx.x = row block (BM=128 rows), blockIdx.y = neg chunk
__global__ __launch_bounds__(256, 2) void iw_main(
    const unsigned short* __restrict__ qb, const unsigned short* __restrict__ nb,
    float2* __restrict__ partial)
{
    constexpr int BM = 128, BN = 64, NIT = CHUNK / BN;   // 32 iters
    __shared__ alignas(16) unsigned short q_lds[BM * DIM]; // 32 KB (swizzled 16B blocks)
    __shared__ alignas(16) unsigned short n_lds[BN * DIM]; // 16 KB

    const int tid  = threadIdx.x;
    const int lane = tid & 63;
    const int w    = tid >> 6;        // wave 0..3, owns 32 query rows
    const int quad = lane >> 4;
    const int c0   = lane & 15;

    const int row0   = blockIdx.x * BM;
    const int nbase0 = blockIdx.y * CHUNK;

    // ---- stage Q tile: 2048 x 16B blocks, XOR-swizzled via source address ----
#pragma unroll
    for (int p = 0; p < 8; ++p) {
        int t   = w * 8 + p;
        int idx = t * 64 + lane;
        int r   = idx >> 4;
        int kb  = (idx & 15) ^ (r & 15);
        async_load16(qb + (size_t)(row0 + r) * DIM + kb * 8, q_lds + t * 512);
    }
    // ---- stage neg tile 0 (offsets reused every iter) ----
    int nro[4], ndst[4];
#pragma unroll
    for (int p = 0; p < 4; ++p) {
        int t   = w * 4 + p;
        int idx = t * 64 + lane;
        int r   = idx >> 4;
        int kb  = (idx & 15) ^ (r & 15);
        nro[p]  = r * DIM + kb * 8;
        ndst[p] = t * 512;
        async_load16(nb + (size_t)nbase0 * DIM + nro[p], n_lds + ndst[p]);
    }
    __syncthreads();

    // ---- A fragments: register-resident for the whole kernel ----
    bf16x8 afrag[2][4];
#pragma unroll
    for (int rs = 0; rs < 2; ++rs)
#pragma unroll
        for (int ks = 0; ks < 4; ++ks) {
            int rl  = w * 32 + rs * 16 + c0;             // rl & 15 == c0
            int blk = rl * 16 + ((ks * 4 + quad) ^ c0);
            afrag[rs][ks] = *reinterpret_cast<const bf16x8*>(q_lds + blk * 8);
        }

    float m_s[2][4], l_s[2][4];
#pragma unroll
    for (int rs = 0; rs < 2; ++rs)
#pragma unroll
        for (int i = 0; i < 4; ++i) { m_s[rs][i] = -1e30f; l_s[rs][i] = 0.f; }

    const f32x4 zero4 = {0.f, 0.f, 0.f, 0.f};

    for (int it = 0; it < NIT; ++it) {
        f32x4 acc[2][4];
#pragma unroll
        for (int rs = 0; rs < 2; ++rs)
#pragma unroll
            for (int ns = 0; ns < 4; ++ns) acc[rs][ns] = zero4;

#pragma unroll
        for (int ns = 0; ns < 4; ++ns) {
#pragma unroll
            for (int ks = 0; ks < 4; ++ks) {
                int blk = (ns * 16 + c0) * 16 + ((ks * 4 + quad) ^ c0);
                bf16x8 b = *reinterpret_cast<const bf16x8*>(n_lds + blk * 8);
                acc[0][ns] = __builtin_amdgcn_mfma_f32_16x16x32_bf16(afrag[0][ks], b, acc[0][ns], 0, 0, 0);
                acc[1][ns] = __builtin_amdgcn_mfma_f32_16x16x32_bf16(afrag[1][ks], b, acc[1][ns], 0, 0, 0);
            }
        }
        __syncthreads();                   // all waves done reading n_lds
        if (it + 1 < NIT) {                // async prefetch next tile
            const unsigned short* src = nb + (size_t)(nbase0 + (it + 1) * BN) * DIM;
#pragma unroll
            for (int p = 0; p < 4; ++p) async_load16(src + nro[p], n_lds + ndst[p]);
        }
        // per-lane online logsumexp update (pure VALU, overlaps staging)
#pragma unroll
        for (int rs = 0; rs < 2; ++rs) {
#pragma unroll
            for (int i = 0; i < 4; ++i) {
                float y0 = acc[rs][0][i], y1 = acc[rs][1][i];
                float y2 = acc[rs][2][i], y3 = acc[rs][3][i];
                float mx = fmaxf(fmaxf(y0, y1), fmaxf(y2, y3));
                float m0 = m_s[rs][i];
                float nm = fmaxf(m0, mx);
                float t  = __builtin_amdgcn_exp2f(y0 - nm) + __builtin_amdgcn_exp2f(y1 - nm)
                         + __builtin_amdgcn_exp2f(y2 - nm) + __builtin_amdgcn_exp2f(y3 - nm);
                l_s[rs][i] = l_s[rs][i] * __builtin_amdgcn_exp2f(m0 - nm) + t;
                m_s[rs][i] = nm;
            }
        }
        __syncthreads();                   // staged tile it+1 complete
    }

    // ---- merge (m,l) across the 16 lanes of each quad-row group ----
#pragma unroll
    for (int rs = 0; rs < 2; ++rs) {
#pragma unroll
        for (int i = 0; i < 4; ++i) {
            float m = m_s[rs][i], l = l_s[rs][i];
#pragma unroll
            for (int s = 1; s < 16; s <<= 1) {
                float om = __shfl_xor(m, s, 64);
                float ol = __shfl_xor(l, s, 64);
                float nm = fmaxf(m, om);
                l = l * __builtin_amdgcn_exp2f(m - nm) + ol * __builtin_amdgcn_exp2f(om - nm);
                m = nm;
            }
            if (c0 == 0) {
                int grow = row0 + w * 32 + rs * 16 + quad * 4 + i;
                partial[(size_t)blockIdx.y * NQ + grow] = make_float2(m, l);
            }
        }
    }
}

// ---------------- kernel 4: merge chunks + mean reduce ----------------
__global__ __launch_bounds__(256) void iw_merge(
    const float2* __restrict__ partial, float* __restrict__ out)
{
    const int tid = threadIdx.x;
    const int row = blockIdx.x * 256 + tid;   // 32 blocks * 256 = 8192
    float M = -1e30f, L = 0.f;
#pragma unroll
    for (int c = 0; c < SPLIT; ++c) {
        float2 p = partial[(size_t)c * NQ + row];
        float nm = fmaxf(M, p.x);
        L = L * __builtin_amdgcn_exp2f(M - nm) + p.y * __builtin_amdgcn_exp2f(p.x - nm);
        M = nm;
    }
    float lse = LN2 * (M + __log2f(L));       // natural-log LSE of scores/tau
    float v = lse * (1.0f / (float)NQ);
    v = waveReduceSum(v);
    __shared__ float red[4];
    if ((tid & 63) == 0) red[tid >> 6] = v;
    __syncthreads();
    if (tid == 0) atomicAdd(out, red[0] + red[1] + red[2] + red[3]);
}

// ---------------- launch ----------------
extern "C" void kernel_launch(void* const* d_in, const int* in_sizes, int n_in,
                              void* d_out, int out_size, void* d_ws, size_t ws_size,
                              hipStream_t stream) {
    const float* q   = (const float*)d_in[0];
    const float* pos = (const float*)d_in[1];
    const float* neg = (const float*)d_in[2];
    float* out = (float*)d_out;

    unsigned short* qb = (unsigned short*)d_ws;                    // 2 MB
    unsigned short* nb = qb + (size_t)NQ * DIM;                    // 4 MB
    float2* partial    = (float2*)(nb + (size_t)NNEG * DIM);       // 512 KB

    iw_prep <<<3072, 256, 0, stream>>>(q, neg, qb, nb, out);
    iw_pos  <<<128,  256, 0, stream>>>(q, pos, out);
    iw_main <<<dim3(64, SPLIT), 256, 0, stream>>>(qb, nb, partial);
    iw_merge<<<32,   256, 0, stream>>>(partial, out);
}